// Round 1
// baseline (1200.027 us; speedup 1.0000x reference)
//
#include <hip/hip_runtime.h>
#include <hip/hip_bf16.h>

#define NT   4096
#define DIMM 512
#define NH   8
#define DKK  64
#define FFD  2048

typedef __hip_bfloat16 bf16;
typedef __bf16 bf8v __attribute__((ext_vector_type(8)));
typedef float  f4v  __attribute__((ext_vector_type(4)));

#define MFMA16 __builtin_amdgcn_mfma_f32_16x16x32_bf16

__device__ __forceinline__ void gll16(const void* g, void* l) {
    __builtin_amdgcn_global_load_lds(
        (__attribute__((address_space(1))) void*)(void*)g,
        (__attribute__((address_space(3))) void*)l, 16, 0, 0);
}

// ---------------- cast f32 -> bf16 ----------------
__global__ __launch_bounds__(256) void k_cast(const float* __restrict__ in,
                                              bf16* __restrict__ out, int n) {
    int i = blockIdx.x * 256 + threadIdx.x;
    if (i < n) out[i] = __float2bfloat16(in[i]);
}

// ---------------- transpose f32[R][C] -> bf16[C][R] ----------------
__global__ __launch_bounds__(256) void k_transpose_f32(const float* __restrict__ in,
                                                       bf16* __restrict__ out, int R, int C) {
    __shared__ float t[32][33];
    int r0 = blockIdx.y * 32, c0 = blockIdx.x * 32;
    int tx = threadIdx.x & 31, ty0 = threadIdx.x >> 5;
#pragma unroll
    for (int i = 0; i < 4; ++i) {
        int ty = ty0 + i * 8;
        t[ty][tx] = in[(size_t)(r0 + ty) * C + c0 + tx];
    }
    __syncthreads();
#pragma unroll
    for (int i = 0; i < 4; ++i) {
        int ty = ty0 + i * 8;
        out[(size_t)(c0 + ty) * R + r0 + tx] = __float2bfloat16(t[tx][ty]);
    }
}

// ---------------- transpose bf16[R][C] -> bf16[C][R] ----------------
__global__ __launch_bounds__(256) void k_transpose_bf16(const bf16* __restrict__ in,
                                                        bf16* __restrict__ out, int R, int C) {
    __shared__ bf16 t[32][33];
    int r0 = blockIdx.y * 32, c0 = blockIdx.x * 32;
    int tx = threadIdx.x & 31, ty0 = threadIdx.x >> 5;
#pragma unroll
    for (int i = 0; i < 4; ++i) {
        int ty = ty0 + i * 8;
        t[ty][tx] = in[(size_t)(r0 + ty) * C + c0 + tx];
    }
    __syncthreads();
#pragma unroll
    for (int i = 0; i < 4; ++i) {
        int ty = ty0 + i * 8;
        out[(size_t)(c0 + ty) * R + r0 + tx] = t[tx][ty];
    }
}

// ---------------- bf16 MFMA GEMM, 128x128 tile, BK=32 ----------------
// mode 0: QKV segmented bf16 outs (seg0 scaled by 1/8)
// mode 1: bf16 out with exact GELU (out_q, stride N)
// mode 2: f32 out = acc + bias + resid (out_f, stride N)
__global__ __launch_bounds__(256)
void k_gemm(const bf16* __restrict__ A, const bf16* __restrict__ Bt,
            const float* __restrict__ bias_q, const float* __restrict__ bias_k,
            const float* __restrict__ bias_v,
            bf16* __restrict__ out_q, bf16* __restrict__ out_k, bf16* __restrict__ out_v,
            float* __restrict__ out_f, const float* __restrict__ resid,
            int M, int N, int K, int mode)
{
    __shared__ __align__(16) bf16 As[128 * 32];
    __shared__ __align__(16) bf16 Bs[128 * 32];
    const int tid = threadIdx.x;
    const int lane = tid & 63;
    const int wv = tid >> 6;
    const int wm = wv >> 1, wn = wv & 1;
    const int q = lane >> 4, ln = lane & 15;
    const int m0 = blockIdx.y * 128, n0 = blockIdx.x * 128;

    const f4v zf = {0.f, 0.f, 0.f, 0.f};
    f4v acc[4][4];
#pragma unroll
    for (int x = 0; x < 4; ++x)
#pragma unroll
        for (int y = 0; y < 4; ++y) acc[x][y] = zf;

    for (int k0 = 0; k0 < K; k0 += 32) {
        __syncthreads();
#pragma unroll
        for (int i = 0; i < 2; ++i) {
            int c = i * 256 + tid;
            int row = c >> 2, off = (c & 3) * 16;
            gll16((const char*)(A + (size_t)(m0 + row) * K + k0) + off,
                  (char*)As + (size_t)(i * 256 + wv * 64) * 16);
            gll16((const char*)(Bt + (size_t)(n0 + row) * K + k0) + off,
                  (char*)Bs + (size_t)(i * 256 + wv * 64) * 16);
        }
        __syncthreads();
        bf8v af[4], bfv[4];
#pragma unroll
        for (int x = 0; x < 4; ++x) {
            af[x]  = *(const bf8v*)((const char*)As + (size_t)(wm * 64 + x * 16 + ln) * 64 + q * 16);
            bfv[x] = *(const bf8v*)((const char*)Bs + (size_t)(wn * 64 + x * 16 + ln) * 64 + q * 16);
        }
#pragma unroll
        for (int x = 0; x < 4; ++x)
#pragma unroll
            for (int y = 0; y < 4; ++y)
                acc[x][y] = MFMA16(af[x], bfv[y], acc[x][y], 0, 0, 0);
    }

#pragma unroll
    for (int x = 0; x < 4; ++x) {
        int row = m0 + wm * 64 + x * 16 + q * 4;
#pragma unroll
        for (int y = 0; y < 4; ++y) {
            int col = n0 + wn * 64 + y * 16 + ln;
            if (mode == 0) {
                int seg = col >> 9;
                int cl = col & 511;
                const float* bp = (seg == 0) ? bias_q : ((seg == 1) ? bias_k : bias_v);
                bf16* op = (seg == 0) ? out_q : ((seg == 1) ? out_k : out_v);
                float sc = (seg == 0) ? 0.125f : 1.0f;
                float bb = bp[cl];
#pragma unroll
                for (int r = 0; r < 4; ++r)
                    op[(size_t)(row + r) * 512 + cl] = __float2bfloat16((acc[x][y][r] + bb) * sc);
            } else if (mode == 1) {
                float bb = bias_q[col];
#pragma unroll
                for (int r = 0; r < 4; ++r) {
                    float v = acc[x][y][r] + bb;
                    v = 0.5f * v * (1.0f + erff(v * 0.70710678118f));
                    out_q[(size_t)(row + r) * N + col] = __float2bfloat16(v);
                }
            } else {
                float bb = bias_q[col];
#pragma unroll
                for (int r = 0; r < 4; ++r)
                    out_f[(size_t)(row + r) * N + col] =
                        acc[x][y][r] + bb + resid[(size_t)(row + r) * N + col];
            }
        }
    }
}

// ---------------- fused flash attention + edge bias ----------------
// block = 16 query rows x all 8 heads (wave = head); loop m in tiles of 32
__global__ __launch_bounds__(512)
void k_attn(const bf16* __restrict__ Qb,  // [NT][512], pre-scaled by 1/8
            const bf16* __restrict__ Kb,  // [NT][512]
            const bf16* __restrict__ Vt,  // [512][NT]  row = h*64+d
            const float* __restrict__ edge,  // [NT][NT][9]
            const float* __restrict__ We,    // [9][8]
            const float* __restrict__ be,    // [8]
            float* __restrict__ out)         // [NT][512]
{
    __shared__ __align__(16) bf16 Ks[32 * 512];       // 32 KB, xor-swizzled chunks
    __shared__ __align__(16) bf16 Ps[NH * 16 * 40];   // padded stride 40
    __shared__ bf16 Bs[NH * 16 * 32];
    __shared__ float WeS[72];
    __shared__ float beS[8];

    const int tid = threadIdx.x;
    const int lane = tid & 63;
    const int h = tid >> 6;
    const int q = lane >> 4, ln = lane & 15;
    const int n0 = blockIdx.x * 16;

    if (tid < 72) WeS[tid] = We[tid];
    if (tid < 8) beS[tid] = be[tid];

    bf8v qf0, qf1;
    {
        const bf16* qp = Qb + (size_t)(n0 + ln) * DIMM + h * DKK + q * 8;
        qf0 = *(const bf8v*)qp;
        qf1 = *(const bf8v*)(qp + 32);
    }
    const f4v zf = {0.f, 0.f, 0.f, 0.f};
    f4v Oc[4] = {zf, zf, zf, zf};
    float Mr[4], Lr[4];
#pragma unroll
    for (int r = 0; r < 4; ++r) { Mr[r] = -3e38f; Lr[r] = 0.f; }

    for (int m0 = 0; m0 < NT; m0 += 32) {
        __syncthreads();
        // stage K tile (32 rows x 1024B) with xor swizzle on 16B chunks
#pragma unroll
        for (int i = 0; i < 4; ++i) {
            int p = i * 512 + tid;
            int row = p >> 6;
            int cc = (p & 63) ^ (row & 7);
            gll16((const char*)(Kb + (size_t)(m0 + row) * DIMM) + cc * 16,
                  (char*)Ks + (size_t)(i * 512 + h * 64) * 16);
        }
        // edge bias: thread -> (n_local, m_local), all 8 heads
        {
            int nl = tid >> 5, ml = tid & 31;
            const float* ep = edge + ((size_t)(n0 + nl) * NT + (m0 + ml)) * 9;
            float ea[9];
#pragma unroll
            for (int e = 0; e < 9; ++e) ea[e] = ep[e];
#pragma unroll
            for (int hh = 0; hh < 8; ++hh) {
                float s = beS[hh];
#pragma unroll
                for (int e = 0; e < 9; ++e) s = fmaf(ea[e], WeS[e * 8 + hh], s);
                Bs[(hh * 16 + nl) * 32 + ml] = __float2bfloat16(s);
            }
        }
        __syncthreads();

        // prefetch V frags (direct global, LLC-resident)
        bf8v vf[4];
#pragma unroll
        for (int dg = 0; dg < 4; ++dg)
            vf[dg] = *(const bf8v*)(Vt + (size_t)(h * DKK + dg * 16 + ln) * NT + m0 + q * 8);

        // S = Q K^T (two 16-col sub-tiles of m)
        f4v S0 = zf, S1 = zf;
#pragma unroll
        for (int dc = 0; dc < 2; ++dc) {
            bf8v qf = (dc == 0) ? qf0 : qf1;
            int ch = h * 8 + dc * 4 + q;
            int r0 = ln, r1 = 16 + ln;
            bf8v k0 = *(const bf8v*)((const char*)Ks + (size_t)r0 * 1024 + ((ch ^ (r0 & 7)) * 16));
            bf8v k1 = *(const bf8v*)((const char*)Ks + (size_t)r1 * 1024 + ((ch ^ (r1 & 7)) * 16));
            S0 = MFMA16(qf, k0, S0, 0, 0, 0);
            S1 = MFMA16(qf, k1, S1, 0, 0, 0);
        }
        // add edge bias (C-layout: row = q*4+r, col = lane&15)
#pragma unroll
        for (int r = 0; r < 4; ++r) {
            S0[r] += __bfloat162float(Bs[(h * 16 + q * 4 + r) * 32 + ln]);
            S1[r] += __bfloat162float(Bs[(h * 16 + q * 4 + r) * 32 + 16 + ln]);
        }
        // online softmax over this 32-wide key tile
#pragma unroll
        for (int r = 0; r < 4; ++r) {
            float v = fmaxf(S0[r], S1[r]);
#pragma unroll
            for (int off = 1; off < 16; off <<= 1) v = fmaxf(v, __shfl_xor(v, off));
            float Mn = fmaxf(Mr[r], v);
            float al = __expf(Mr[r] - Mn);
            Mr[r] = Mn;
            float p0 = __expf(S0[r] - Mn);
            float p1 = __expf(S1[r] - Mn);
            S0[r] = p0; S1[r] = p1;
            float sm = p0 + p1;
#pragma unroll
            for (int off = 1; off < 16; off <<= 1) sm += __shfl_xor(sm, off);
            Lr[r] = Lr[r] * al + sm;
            Oc[0][r] *= al; Oc[1][r] *= al; Oc[2][r] *= al; Oc[3][r] *= al;
        }
        // P: C-layout -> LDS -> A-layout (per-head region, same-wave RAW is in-order)
#pragma unroll
        for (int r = 0; r < 4; ++r) {
            Ps[h * 640 + (q * 4 + r) * 40 + ln]      = __float2bfloat16(S0[r]);
            Ps[h * 640 + (q * 4 + r) * 40 + 16 + ln] = __float2bfloat16(S1[r]);
        }
        bf8v pf = *(const bf8v*)(Ps + h * 640 + ln * 40 + q * 8);
#pragma unroll
        for (int dg = 0; dg < 4; ++dg)
            Oc[dg] = MFMA16(pf, vf[dg], Oc[dg], 0, 0, 0);
    }

#pragma unroll
    for (int dg = 0; dg < 4; ++dg)
#pragma unroll
        for (int r = 0; r < 4; ++r)
            out[(size_t)(n0 + q * 4 + r) * DIMM + h * DKK + dg * 16 + ln] = Oc[dg][r] / Lr[r];
}

// ---------------- layernorm (optional residual, optional bf16 copy) ----------------
__global__ __launch_bounds__(256)
void k_ln(const float* __restrict__ a, const float* __restrict__ b,
          const float* __restrict__ g, const float* __restrict__ bet,
          float* __restrict__ outf, bf16* __restrict__ outb)
{
    int row = blockIdx.x, t = threadIdx.x;
    size_t base = (size_t)row * DIMM;
    float v0 = a[base + t], v1 = a[base + t + 256];
    if (b) { v0 += b[base + t]; v1 += b[base + t + 256]; }
    float s1 = v0 + v1, s2 = v0 * v0 + v1 * v1;
#pragma unroll
    for (int off = 1; off < 64; off <<= 1) {
        s1 += __shfl_xor(s1, off);
        s2 += __shfl_xor(s2, off);
    }
    __shared__ float p1[4], p2[4];
    if ((t & 63) == 0) { p1[t >> 6] = s1; p2[t >> 6] = s2; }
    __syncthreads();
    s1 = p1[0] + p1[1] + p1[2] + p1[3];
    s2 = p2[0] + p2[1] + p2[2] + p2[3];
    float mean = s1 * (1.f / 512.f);
    float var = s2 * (1.f / 512.f) - mean * mean;
    float rstd = rsqrtf(var + 1e-5f);
    float o0 = (v0 - mean) * rstd * g[t] + bet[t];
    float o1 = (v1 - mean) * rstd * g[t + 256] + bet[t + 256];
    if (outf) { outf[base + t] = o0; outf[base + t + 256] = o1; }
    if (outb) { outb[base + t] = __float2bfloat16(o0); outb[base + t + 256] = __float2bfloat16(o1); }
}

extern "C" void kernel_launch(void* const* d_in, const int* in_sizes, int n_in,
                              void* d_out, int out_size, void* d_ws, size_t ws_size,
                              hipStream_t stream) {
    (void)in_sizes; (void)n_in; (void)out_size; (void)ws_size;
    const float* x    = (const float*)d_in[0];
    const float* edge = (const float*)d_in[1];
    const float* Wq   = (const float*)d_in[2];
    const float* bq   = (const float*)d_in[3];
    const float* Wk   = (const float*)d_in[4];
    const float* bk   = (const float*)d_in[5];
    const float* Wv   = (const float*)d_in[6];
    const float* bv   = (const float*)d_in[7];
    const float* We   = (const float*)d_in[8];
    const float* be   = (const float*)d_in[9];
    const float* g1   = (const float*)d_in[10];
    const float* b1   = (const float*)d_in[11];
    const float* W1   = (const float*)d_in[12];
    const float* bf1  = (const float*)d_in[13];
    const float* W2   = (const float*)d_in[14];
    const float* bf2  = (const float*)d_in[15];
    const float* g2   = (const float*)d_in[16];
    const float* b2   = (const float*)d_in[17];

    char* w = (char*)d_ws;
    bf16* xb  = (bf16*)w; w += (size_t)NT * DIMM * 2;
    bf16* Wqt = (bf16*)w; w += (size_t)DIMM * DIMM * 2;   // Wqt/Wkt/Wvt must stay adjacent
    bf16* Wkt = (bf16*)w; w += (size_t)DIMM * DIMM * 2;
    bf16* Wvt = (bf16*)w; w += (size_t)DIMM * DIMM * 2;
    bf16* W1t = (bf16*)w; w += (size_t)FFD * DIMM * 2;
    bf16* W2t = (bf16*)w; w += (size_t)DIMM * FFD * 2;
    bf16* Qb  = (bf16*)w; w += (size_t)NT * DIMM * 2;
    bf16* Kb  = (bf16*)w; w += (size_t)NT * DIMM * 2;
    bf16* Vb  = (bf16*)w; w += (size_t)NT * DIMM * 2;
    bf16* Vt  = (bf16*)w; w += (size_t)NT * DIMM * 2;
    float* attn = (float*)w; w += (size_t)NT * DIMM * 4;
    float* y    = (float*)w; w += (size_t)NT * DIMM * 4;
    bf16* yb  = (bf16*)w; w += (size_t)NT * DIMM * 2;
    bf16* h1  = (bf16*)w; w += (size_t)NT * FFD * 2;
    float* z    = (float*)w; w += (size_t)NT * DIMM * 4;

    k_cast<<<NT * DIMM / 256, 256, 0, stream>>>(x, xb, NT * DIMM);
    k_transpose_f32<<<dim3(16, 16), 256, 0, stream>>>(Wq, Wqt, 512, 512);
    k_transpose_f32<<<dim3(16, 16), 256, 0, stream>>>(Wk, Wkt, 512, 512);
    k_transpose_f32<<<dim3(16, 16), 256, 0, stream>>>(Wv, Wvt, 512, 512);
    k_transpose_f32<<<dim3(64, 16), 256, 0, stream>>>(W1, W1t, 512, 2048);
    k_transpose_f32<<<dim3(16, 64), 256, 0, stream>>>(W2, W2t, 2048, 512);

    // fused QKV: N = 1536 over adjacent Wqt|Wkt|Wvt
    k_gemm<<<dim3(12, 32), 256, 0, stream>>>(xb, Wqt, bq, bk, bv, Qb, Kb, Vb,
                                             nullptr, nullptr, NT, 1536, 512, 0);
    k_transpose_bf16<<<dim3(16, 128), 256, 0, stream>>>(Vb, Vt, NT, DIMM);

    k_attn<<<256, 512, 0, stream>>>(Qb, Kb, Vt, edge, We, be, attn);

    k_ln<<<NT, 256, 0, stream>>>(x, attn, g1, b1, y, yb);

    k_gemm<<<dim3(16, 32), 256, 0, stream>>>(yb, W1t, bf1, nullptr, nullptr, h1,
                                             nullptr, nullptr, nullptr, nullptr,
                                             NT, FFD, DIMM, 1);
    k_gemm<<<dim3(4, 32), 256, 0, stream>>>(h1, W2t, bf2, nullptr, nullptr, nullptr,
                                            nullptr, nullptr, z, y, NT, DIMM, FFD, 2);

    k_ln<<<NT, 256, 0, stream>>>(z, nullptr, g2, b2, (float*)d_out, nullptr);
}

// Round 2
// 1103.235 us; speedup vs baseline: 1.0877x; 1.0877x over previous
//
#include <hip/hip_runtime.h>
#include <hip/hip_bf16.h>

#define NT   4096
#define DIMM 512
#define NH   8
#define DKK  64
#define FFD  2048
#define SPLIT 2
#define KT    64
#define KITERS (NT / SPLIT / KT)   // 32

typedef __hip_bfloat16 bf16;
typedef __bf16 bf8v __attribute__((ext_vector_type(8)));
typedef float  f4v  __attribute__((ext_vector_type(4)));

#define MFMA16 __builtin_amdgcn_mfma_f32_16x16x32_bf16

__device__ __forceinline__ void gll16(const void* g, void* l) {
    __builtin_amdgcn_global_load_lds(
        (__attribute__((address_space(1))) void*)(void*)g,
        (__attribute__((address_space(3))) void*)l, 16, 0, 0);
}

// ---------------- cast f32 -> bf16 ----------------
__global__ __launch_bounds__(256) void k_cast(const float* __restrict__ in,
                                              bf16* __restrict__ out, int n) {
    int i = blockIdx.x * 256 + threadIdx.x;
    if (i < n) out[i] = __float2bfloat16(in[i]);
}

// ---------------- transpose f32[R][C] -> bf16[C][R] ----------------
__global__ __launch_bounds__(256) void k_transpose_f32(const float* __restrict__ in,
                                                       bf16* __restrict__ out, int R, int C) {
    __shared__ float t[32][33];
    int r0 = blockIdx.y * 32, c0 = blockIdx.x * 32;
    int tx = threadIdx.x & 31, ty0 = threadIdx.x >> 5;
#pragma unroll
    for (int i = 0; i < 4; ++i) {
        int ty = ty0 + i * 8;
        t[ty][tx] = in[(size_t)(r0 + ty) * C + c0 + tx];
    }
    __syncthreads();
#pragma unroll
    for (int i = 0; i < 4; ++i) {
        int ty = ty0 + i * 8;
        out[(size_t)(c0 + ty) * R + r0 + tx] = __float2bfloat16(t[tx][ty]);
    }
}

// ---------------- transpose bf16[R][C] -> bf16[C][R] ----------------
__global__ __launch_bounds__(256) void k_transpose_bf16(const bf16* __restrict__ in,
                                                        bf16* __restrict__ out, int R, int C) {
    __shared__ bf16 t[32][33];
    int r0 = blockIdx.y * 32, c0 = blockIdx.x * 32;
    int tx = threadIdx.x & 31, ty0 = threadIdx.x >> 5;
#pragma unroll
    for (int i = 0; i < 4; ++i) {
        int ty = ty0 + i * 8;
        t[ty][tx] = in[(size_t)(r0 + ty) * C + c0 + tx];
    }
    __syncthreads();
#pragma unroll
    for (int i = 0; i < 4; ++i) {
        int ty = ty0 + i * 8;
        out[(size_t)(c0 + ty) * R + r0 + tx] = t[tx][ty];
    }
}

// ---------------- bf16 MFMA GEMM, 128x128 tile, BK=32 ----------------
__global__ __launch_bounds__(256)
void k_gemm(const bf16* __restrict__ A, const bf16* __restrict__ Bt,
            const float* __restrict__ bias_q, const float* __restrict__ bias_k,
            const float* __restrict__ bias_v,
            bf16* __restrict__ out_q, bf16* __restrict__ out_k, bf16* __restrict__ out_v,
            float* __restrict__ out_f, const float* __restrict__ resid,
            int M, int N, int K, int mode)
{
    __shared__ __align__(16) bf16 As[128 * 32];
    __shared__ __align__(16) bf16 Bs[128 * 32];
    const int tid = threadIdx.x;
    const int lane = tid & 63;
    const int wv = tid >> 6;
    const int wm = wv >> 1, wn = wv & 1;
    const int q = lane >> 4, ln = lane & 15;
    const int m0 = blockIdx.y * 128, n0 = blockIdx.x * 128;

    const f4v zf = {0.f, 0.f, 0.f, 0.f};
    f4v acc[4][4];
#pragma unroll
    for (int x = 0; x < 4; ++x)
#pragma unroll
        for (int y = 0; y < 4; ++y) acc[x][y] = zf;

    for (int k0 = 0; k0 < K; k0 += 32) {
        __syncthreads();
#pragma unroll
        for (int i = 0; i < 2; ++i) {
            int c = i * 256 + tid;
            int row = c >> 2, off = (c & 3) * 16;
            gll16((const char*)(A + (size_t)(m0 + row) * K + k0) + off,
                  (char*)As + (size_t)(i * 256 + wv * 64) * 16);
            gll16((const char*)(Bt + (size_t)(n0 + row) * K + k0) + off,
                  (char*)Bs + (size_t)(i * 256 + wv * 64) * 16);
        }
        __syncthreads();
        bf8v af[4], bfv[4];
#pragma unroll
        for (int x = 0; x < 4; ++x) {
            af[x]  = *(const bf8v*)((const char*)As + (size_t)(wm * 64 + x * 16 + ln) * 64 + q * 16);
            bfv[x] = *(const bf8v*)((const char*)Bs + (size_t)(wn * 64 + x * 16 + ln) * 64 + q * 16);
        }
#pragma unroll
        for (int x = 0; x < 4; ++x)
#pragma unroll
            for (int y = 0; y < 4; ++y)
                acc[x][y] = MFMA16(af[x], bfv[y], acc[x][y], 0, 0, 0);
    }

#pragma unroll
    for (int x = 0; x < 4; ++x) {
        int row = m0 + wm * 64 + x * 16 + q * 4;
#pragma unroll
        for (int y = 0; y < 4; ++y) {
            int col = n0 + wn * 64 + y * 16 + ln;
            if (mode == 0) {
                int seg = col >> 9;
                int cl = col & 511;
                const float* bp = (seg == 0) ? bias_q : ((seg == 1) ? bias_k : bias_v);
                bf16* op = (seg == 0) ? out_q : ((seg == 1) ? out_k : out_v);
                float sc = (seg == 0) ? 0.125f : 1.0f;
                float bb = bp[cl];
#pragma unroll
                for (int r = 0; r < 4; ++r)
                    op[(size_t)(row + r) * 512 + cl] = __float2bfloat16((acc[x][y][r] + bb) * sc);
            } else if (mode == 1) {
                float bb = bias_q[col];
#pragma unroll
                for (int r = 0; r < 4; ++r) {
                    float v = acc[x][y][r] + bb;
                    v = 0.5f * v * (1.0f + erff(v * 0.70710678118f));
                    out_q[(size_t)(row + r) * N + col] = __float2bfloat16(v);
                }
            } else {
                float bb = bias_q[col];
#pragma unroll
                for (int r = 0; r < 4; ++r)
                    out_f[(size_t)(row + r) * N + col] =
                        acc[x][y][r] + bb + resid[(size_t)(row + r) * N + col];
            }
        }
    }
}

// ---------------- fused flash attention + edge bias (split-K, fixed-max softmax) ---
// grid (SPLIT, 256); block = 512 = 8 waves; wave = head; 16 query rows/block.
// Partials: Opart[sp][n][512] unnormalized, Lpart[sp][n][8].
__global__ __launch_bounds__(512, 4)
void k_attn(const bf16* __restrict__ Qb,  // [NT][512], pre-scaled by 1/8
            const bf16* __restrict__ Kb,  // [NT][512]
            const bf16* __restrict__ Vt,  // [512][NT]  row = h*64+d
            const float* __restrict__ edge,  // [NT][NT][9]
            const float* __restrict__ We,    // [9][8]
            const float* __restrict__ be,    // [8]
            float* __restrict__ Opart,       // [SPLIT][NT][512]
            float* __restrict__ Lpart)       // [SPLIT][NT][8]
{
    __shared__ bf16 Bsb[2 * NH * 16 * 66];          // double-buffered bias tile 16x64 (pad 66)
    __shared__ __align__(16) bf16 Ps[NH * 16 * 72]; // P roundtrip, pad 72 (16B-aligned rows)
    __shared__ float WeS[72], beS[8];

    const int tid = threadIdx.x;
    const int lane = tid & 63;
    const int h = tid >> 6;
    const int q = lane >> 4, ln = lane & 15;
    const int sp = blockIdx.x;
    const int n0 = blockIdx.y * 16;
    const int mbase = sp * (NT / SPLIT);

    if (tid < 72) WeS[tid] = We[tid];
    if (tid < 8) beS[tid] = be[tid];
    __syncthreads();

    bf8v qf0, qf1;
    {
        const bf16* qp = Qb + (size_t)(n0 + ln) * DIMM + h * DKK + q * 8;
        qf0 = *(const bf8v*)qp;
        qf1 = *(const bf8v*)(qp + 32);
    }

    const int nl = tid >> 5, ml = tid & 31;  // edge pair (n0+nl, m+ml) and (.., m+ml+32)
    float ea[2][9];
#pragma unroll
    for (int j = 0; j < 2; ++j) {
        const float* ep = edge + ((size_t)(n0 + nl) * NT + (mbase + ml + j * 32)) * 9;
#pragma unroll
        for (int e = 0; e < 9; ++e) ea[j][e] = ep[e];
    }

    const f4v zf = {0.f, 0.f, 0.f, 0.f};
    f4v Oc[4] = {zf, zf, zf, zf};
    float Lr[4] = {0.f, 0.f, 0.f, 0.f};

    for (int it = 0; it < KITERS; ++it) {
        const int m0 = mbase + it * KT;

        // K frags for this iter (L2-resident; issued early to hide latency)
        bf8v kf[2][4];
#pragma unroll
        for (int dc = 0; dc < 2; ++dc)
#pragma unroll
            for (int st = 0; st < 4; ++st)
                kf[dc][st] = *(const bf8v*)(Kb + (size_t)(m0 + st * 16 + ln) * DIMM
                                            + h * DKK + dc * 32 + q * 8);

        // edge bias for this iter (from ea prefetched last iter)
        bf16* Bw = Bsb + (it & 1) * (NH * 16 * 66);
#pragma unroll
        for (int hh = 0; hh < 8; ++hh) {
            float s0 = beS[hh], s1 = beS[hh];
#pragma unroll
            for (int e = 0; e < 9; ++e) {
                float wv = WeS[e * 8 + hh];
                s0 = fmaf(ea[0][e], wv, s0);
                s1 = fmaf(ea[1][e], wv, s1);
            }
            Bw[hh * 1056 + nl * 66 + ml]      = __float2bfloat16(s0);
            Bw[hh * 1056 + nl * 66 + ml + 32] = __float2bfloat16(s1);
        }

        // prefetch edge for next iter
        {
            int itn = (it + 1 < KITERS) ? it + 1 : it;
            int mp = mbase + itn * KT;
#pragma unroll
            for (int j = 0; j < 2; ++j) {
                const float* ep = edge + ((size_t)(n0 + nl) * NT + (mp + ml + j * 32)) * 9;
#pragma unroll
                for (int e = 0; e < 9; ++e) ea[j][e] = ep[e];
            }
        }
        __syncthreads();

        // V frags (issued post-barrier; hidden by S+exp phase)
        bf8v vf[4][2];
#pragma unroll
        for (int dg = 0; dg < 4; ++dg)
#pragma unroll
            for (int kk = 0; kk < 2; ++kk)
                vf[dg][kk] = *(const bf8v*)(Vt + (size_t)(h * DKK + dg * 16 + ln) * NT
                                            + m0 + kk * 32 + q * 8);

        // S = Q K^T + bias; p = exp(s - 16); accumulate L
        const bf16* Br = Bsb + (it & 1) * (NH * 16 * 66) + h * 1056;
#pragma unroll
        for (int st = 0; st < 4; ++st) {
            f4v S = zf;
            S = MFMA16(qf0, kf[0][st], S, 0, 0, 0);
            S = MFMA16(qf1, kf[1][st], S, 0, 0, 0);
#pragma unroll
            for (int r = 0; r < 4; ++r) {
                float b = __bfloat162float(Br[(q * 4 + r) * 66 + st * 16 + ln]);
                float p = __expf(S[r] + b - 16.f);
                Lr[r] += p;
                Ps[h * 1152 + (q * 4 + r) * 72 + st * 16 + ln] = __float2bfloat16(p);
            }
        }
        // PV (P roundtrip is wave-local; in-order within wave)
#pragma unroll
        for (int kk = 0; kk < 2; ++kk) {
            bf8v pf = *(const bf8v*)(Ps + h * 1152 + ln * 72 + kk * 32 + q * 8);
#pragma unroll
            for (int dg = 0; dg < 4; ++dg)
                Oc[dg] = MFMA16(pf, vf[dg][kk], Oc[dg], 0, 0, 0);
        }
    }

    // reduce L across the 16 lanes of each quad (keys dim)
#pragma unroll
    for (int r = 0; r < 4; ++r) {
#pragma unroll
        for (int off = 1; off < 16; off <<= 1)
            Lr[r] += __shfl_xor(Lr[r], off);
    }

    float* Op = Opart + (size_t)sp * NT * DIMM;
#pragma unroll
    for (int dg = 0; dg < 4; ++dg)
#pragma unroll
        for (int r = 0; r < 4; ++r)
            Op[(size_t)(n0 + q * 4 + r) * DIMM + h * DKK + dg * 16 + ln] = Oc[dg][r];
    if (ln == 0) {
#pragma unroll
        for (int r = 0; r < 4; ++r)
            Lpart[(size_t)sp * NT * NH + (size_t)(n0 + q * 4 + r) * NH + h] = Lr[r];
    }
}

// ---------------- merge attention partials + residual + layernorm ----------------
__global__ __launch_bounds__(256)
void k_ln_merge(const float* __restrict__ x,
                const float* __restrict__ O0, const float* __restrict__ O1,
                const float* __restrict__ Lp,   // [2][NT][8]
                const float* __restrict__ g, const float* __restrict__ bet,
                float* __restrict__ outf, bf16* __restrict__ outb)
{
    int row = blockIdx.x, t = threadIdx.x;
    size_t base = (size_t)row * DIMM;
    int c0 = t, c1 = t + 256;
    float La = Lp[(size_t)row * 8 + (c0 >> 6)] + Lp[(size_t)NT * 8 + (size_t)row * 8 + (c0 >> 6)];
    float Lb = Lp[(size_t)row * 8 + (c1 >> 6)] + Lp[(size_t)NT * 8 + (size_t)row * 8 + (c1 >> 6)];
    float v0 = x[base + c0] + (O0[base + c0] + O1[base + c0]) / La;
    float v1 = x[base + c1] + (O0[base + c1] + O1[base + c1]) / Lb;
    float s1 = v0 + v1, s2 = v0 * v0 + v1 * v1;
#pragma unroll
    for (int off = 1; off < 64; off <<= 1) {
        s1 += __shfl_xor(s1, off);
        s2 += __shfl_xor(s2, off);
    }
    __shared__ float p1[4], p2[4];
    if ((t & 63) == 0) { p1[t >> 6] = s1; p2[t >> 6] = s2; }
    __syncthreads();
    s1 = p1[0] + p1[1] + p1[2] + p1[3];
    s2 = p2[0] + p2[1] + p2[2] + p2[3];
    float mean = s1 * (1.f / 512.f);
    float var = s2 * (1.f / 512.f) - mean * mean;
    float rstd = rsqrtf(var + 1e-5f);
    float o0 = (v0 - mean) * rstd * g[c0] + bet[c0];
    float o1 = (v1 - mean) * rstd * g[c1] + bet[c1];
    outf[base + c0] = o0; outf[base + c1] = o1;
    outb[base + c0] = __float2bfloat16(o0); outb[base + c1] = __float2bfloat16(o1);
}

// ---------------- layernorm (no residual) ----------------
__global__ __launch_bounds__(256)
void k_ln(const float* __restrict__ a,
          const float* __restrict__ g, const float* __restrict__ bet,
          float* __restrict__ outf)
{
    int row = blockIdx.x, t = threadIdx.x;
    size_t base = (size_t)row * DIMM;
    float v0 = a[base + t], v1 = a[base + t + 256];
    float s1 = v0 + v1, s2 = v0 * v0 + v1 * v1;
#pragma unroll
    for (int off = 1; off < 64; off <<= 1) {
        s1 += __shfl_xor(s1, off);
        s2 += __shfl_xor(s2, off);
    }
    __shared__ float p1[4], p2[4];
    if ((t & 63) == 0) { p1[t >> 6] = s1; p2[t >> 6] = s2; }
    __syncthreads();
    s1 = p1[0] + p1[1] + p1[2] + p1[3];
    s2 = p2[0] + p2[1] + p2[2] + p2[3];
    float mean = s1 * (1.f / 512.f);
    float var = s2 * (1.f / 512.f) - mean * mean;
    float rstd = rsqrtf(var + 1e-5f);
    outf[base + t] = (v0 - mean) * rstd * g[t] + bet[t];
    outf[base + t + 256] = (v1 - mean) * rstd * g[t + 256] + bet[t + 256];
}

extern "C" void kernel_launch(void* const* d_in, const int* in_sizes, int n_in,
                              void* d_out, int out_size, void* d_ws, size_t ws_size,
                              hipStream_t stream) {
    (void)in_sizes; (void)n_in; (void)out_size; (void)ws_size;
    const float* x    = (const float*)d_in[0];
    const float* edge = (const float*)d_in[1];
    const float* Wq   = (const float*)d_in[2];
    const float* bq   = (const float*)d_in[3];
    const float* Wk   = (const float*)d_in[4];
    const float* bk   = (const float*)d_in[5];
    const float* Wv   = (const float*)d_in[6];
    const float* bv   = (const float*)d_in[7];
    const float* We   = (const float*)d_in[8];
    const float* be   = (const float*)d_in[9];
    const float* g1   = (const float*)d_in[10];
    const float* b1   = (const float*)d_in[11];
    const float* W1   = (const float*)d_in[12];
    const float* bf1  = (const float*)d_in[13];
    const float* W2   = (const float*)d_in[14];
    const float* bf2  = (const float*)d_in[15];
    const float* g2   = (const float*)d_in[16];
    const float* b2   = (const float*)d_in[17];

    char* w = (char*)d_ws;
    bf16* xb  = (bf16*)w; w += (size_t)NT * DIMM * 2;
    bf16* Wqt = (bf16*)w; w += (size_t)DIMM * DIMM * 2;   // Wqt/Wkt/Wvt adjacent
    bf16* Wkt = (bf16*)w; w += (size_t)DIMM * DIMM * 2;
    bf16* Wvt = (bf16*)w; w += (size_t)DIMM * DIMM * 2;
    bf16* W1t = (bf16*)w; w += (size_t)FFD * DIMM * 2;
    bf16* W2t = (bf16*)w; w += (size_t)DIMM * FFD * 2;
    bf16* Qb  = (bf16*)w; w += (size_t)NT * DIMM * 2;
    bf16* Kb  = (bf16*)w; w += (size_t)NT * DIMM * 2;
    bf16* Vb  = (bf16*)w; w += (size_t)NT * DIMM * 2;
    bf16* Vt  = (bf16*)w; w += (size_t)NT * DIMM * 2;
    float* Opart = (float*)w; w += (size_t)SPLIT * NT * DIMM * 4;
    float* Lpart = (float*)w; w += (size_t)SPLIT * NT * NH * 4;
    float* y    = (float*)w; w += (size_t)NT * DIMM * 4;
    bf16* yb  = (bf16*)w; w += (size_t)NT * DIMM * 2;
    bf16* h1  = (bf16*)w; w += (size_t)NT * FFD * 2;
    float* z    = (float*)w; w += (size_t)NT * DIMM * 4;

    k_cast<<<NT * DIMM / 256, 256, 0, stream>>>(x, xb, NT * DIMM);
    k_transpose_f32<<<dim3(16, 16), 256, 0, stream>>>(Wq, Wqt, 512, 512);
    k_transpose_f32<<<dim3(16, 16), 256, 0, stream>>>(Wk, Wkt, 512, 512);
    k_transpose_f32<<<dim3(16, 16), 256, 0, stream>>>(Wv, Wvt, 512, 512);
    k_transpose_f32<<<dim3(64, 16), 256, 0, stream>>>(W1, W1t, 512, 2048);
    k_transpose_f32<<<dim3(16, 64), 256, 0, stream>>>(W2, W2t, 2048, 512);

    k_gemm<<<dim3(12, 32), 256, 0, stream>>>(xb, Wqt, bq, bk, bv, Qb, Kb, Vb,
                                             nullptr, nullptr, NT, 1536, 512, 0);
    k_transpose_bf16<<<dim3(16, 128), 256, 0, stream>>>(Vb, Vt, NT, DIMM);

    k_attn<<<dim3(SPLIT, 256), 512, 0, stream>>>(Qb, Kb, Vt, edge, We, be, Opart, Lpart);

    k_ln_merge<<<NT, 256, 0, stream>>>(x, Opart, Opart + (size_t)NT * DIMM, Lpart,
                                       g1, b1, y, yb);

    k_gemm<<<dim3(16, 32), 256, 0, stream>>>(yb, W1t, bf1, nullptr, nullptr, h1,
                                             nullptr, nullptr, nullptr, nullptr,
                                             NT, FFD, DIMM, 1);
    k_gemm<<<dim3(4, 32), 256, 0, stream>>>(h1, W2t, bf2, nullptr, nullptr, nullptr,
                                            nullptr, nullptr, z, y, NT, DIMM, FFD, 2);

    k_ln<<<NT, 256, 0, stream>>>(z, g2, b2, (float*)d_out);
}